// Round 14
// baseline (128.280 us; speedup 1.0000x reference)
//
#include <hip/hip_runtime.h>

// out[b,t,u,v] = ye[b,t,v] + yp[b,u,v]
//   ye = enc@Wc,  yp = pred@Wc + bcv,  Wc = W0@W1,  bcv = b0@W1 + b1.
// R14:
//   D1 prep (452 blocks): [0,128) Wc-GEMM -> WcT[v][d] bf16 (transposed store);
//                         [128,448) x=[enc;pred] fp32->bf16 convert;
//                         [448,452) bcv = b0@W1 + b1 (fp32).
//   D2 gemm_y (320 blocks): Q[1280][1024] fp32 = xbf@WcT (+bcv on pred rows).
//       Clean bf16 staging: 16B load + 16B LDS store per side; double-buffered.
//   D3 bcast (R13-proven): register outer-product, pure NT-store stream.

typedef float vf4 __attribute__((ext_vector_type(4)));
typedef short bf16x8 __attribute__((ext_vector_type(8)));
typedef float f32x4 __attribute__((ext_vector_type(4)));
typedef unsigned short us4 __attribute__((ext_vector_type(4)));

#define PADK 40   // LDS row stride in bf16 (80B)

__device__ __forceinline__ unsigned short f2bf(float f) {
    union { float f; unsigned u; } v; v.f = f;
    const unsigned r = v.u + 0x7FFFu + ((v.u >> 16) & 1u);   // RNE
    return (unsigned short)(r >> 16);
}

// ---------------- D1: prep ----------------
__global__ __launch_bounds__(256) void prep(
    const float* __restrict__ pred, const float* __restrict__ enc,
    const float* __restrict__ W0, const float* __restrict__ b0,
    const float* __restrict__ W1, const float* __restrict__ b1,
    unsigned short* __restrict__ xbf,     // [1280][512] bf16
    unsigned short* __restrict__ WcT,     // [1024][512] bf16 (v-major)
    float* __restrict__ bcv)              // [1024]
{
    __shared__ unsigned short As[64 * PADK];   // Wc-GEMM: [d][h]
    __shared__ unsigned short Bst[64 * PADK];  // Wc-GEMM: [v][h]
    __shared__ float b0s[512];

    const int bid = blockIdx.x;
    const int tid = threadIdx.x;

    if (bid < 128) {
        // ---- Wc = W0@W1, 64x64 tile; C written TRANSPOSED to WcT[v][d] ----
        const int row0 = (bid >> 4) << 6;    // d: 8 tiles
        const int col0 = (bid & 15) << 6;    // v: 16 tiles
        const int w = tid >> 6, lane = tid & 63;
        const int l16 = lane & 15, kq = lane >> 4;

        float4 ar[2], br[2];
        auto loadA = [&](int kb) {
            #pragma unroll
            for (int i = 0; i < 2; ++i) {
                const int idx = tid + (i << 8);
                const int r = idx >> 3, k4 = (idx & 7) << 2;
                ar[i] = *reinterpret_cast<const float4*>(
                    W0 + (size_t)(row0 + r) * 512 + kb + k4);
            }
        };
        auto loadB = [&](int kb) {
            #pragma unroll
            for (int i = 0; i < 2; ++i) {
                const int idx = tid + (i << 8);
                const int kk = idx >> 4, n4 = (idx & 15) << 2;
                br[i] = *reinterpret_cast<const float4*>(
                    W1 + (size_t)(kb + kk) * 1024 + col0 + n4);
            }
        };
        auto stage = [&]() {
            #pragma unroll
            for (int i = 0; i < 2; ++i) {
                const int idx = tid + (i << 8);
                const int r = idx >> 3, k4 = (idx & 7) << 2;
                us4 p = { f2bf(ar[i].x), f2bf(ar[i].y), f2bf(ar[i].z), f2bf(ar[i].w) };
                *reinterpret_cast<us4*>(&As[r * PADK + k4]) = p;
                const int kk = idx >> 4, n4 = (idx & 15) << 2;
                Bst[(n4 + 0) * PADK + kk] = f2bf(br[i].x);
                Bst[(n4 + 1) * PADK + kk] = f2bf(br[i].y);
                Bst[(n4 + 2) * PADK + kk] = f2bf(br[i].z);
                Bst[(n4 + 3) * PADK + kk] = f2bf(br[i].w);
            }
        };

        f32x4 acc[4] = {};
        loadA(0); loadB(0);
        for (int kt = 0; kt < 16; ++kt) {
            __syncthreads();
            stage();
            __syncthreads();
            if (kt < 15) { loadA((kt + 1) << 5); loadB((kt + 1) << 5); }
            bf16x8 a = *reinterpret_cast<const bf16x8*>(&As[(w * 16 + l16) * PADK + kq * 8]);
            #pragma unroll
            for (int nf = 0; nf < 4; ++nf) {
                bf16x8 b = *reinterpret_cast<const bf16x8*>(&Bst[(nf * 16 + l16) * PADK + kq * 8]);
                acc[nf] = __builtin_amdgcn_mfma_f32_16x16x32_bf16(a, b, acc[nf], 0, 0, 0);
            }
        }
        // C/D: col=lane&15 (v), row=kq*4+r (d). Write WcT[v][d], d contiguous.
        const int cr0 = row0 + w * 16 + kq * 4;
        #pragma unroll
        for (int nf = 0; nf < 4; ++nf) {
            const int c = col0 + nf * 16 + l16;
            us4 p = { f2bf(acc[nf][0]), f2bf(acc[nf][1]),
                      f2bf(acc[nf][2]), f2bf(acc[nf][3]) };
            *reinterpret_cast<us4*>(&WcT[(size_t)c * 512 + cr0]) = p;
        }
    } else if (bid < 448) {
        // ---- x convert: [enc(1024 rows); pred(256 rows)] fp32 -> bf16 ----
        const int i = ((bid - 128) << 8) + tid;   // 0..81919, 8 elems each
        const int r = i >> 6;                     // row, 64 threads/row
        const int k8 = (i & 63) << 3;
        const float* src = (r < 1024)
            ? enc + (size_t)r * 512 + k8
            : pred + (size_t)(r - 1024) * 512 + k8;
        const float4 a = *reinterpret_cast<const float4*>(src);
        const float4 c = *reinterpret_cast<const float4*>(src + 4);
        us4 p0 = { f2bf(a.x), f2bf(a.y), f2bf(a.z), f2bf(a.w) };
        us4 p1 = { f2bf(c.x), f2bf(c.y), f2bf(c.z), f2bf(c.w) };
        *reinterpret_cast<us4*>(&xbf[(size_t)r * 512 + k8]) = p0;
        *reinterpret_cast<us4*>(&xbf[(size_t)r * 512 + k8 + 4]) = p1;
    } else {
        // ---- bcv = b0@W1 + b1 (fp32), 4 blocks x 256 v ----
        for (int i = tid; i < 512; i += 256) b0s[i] = b0[i];
        __syncthreads();
        const int v = ((bid - 448) << 8) + tid;   // 0..1023
        float acc = b1[v];
        #pragma unroll 8
        for (int h = 0; h < 512; ++h)
            acc = fmaf(b0s[h], W1[(size_t)h * 1024 + v], acc);
        bcv[v] = acc;
    }
}

// ---------------- D2: Q = xbf @ WcT (+bcv on pred rows) ----------------
__global__ __launch_bounds__(256) void gemm_y(
    const unsigned short* __restrict__ xbf,   // [1280][512]
    const unsigned short* __restrict__ WcT,   // [1024][512]
    const float* __restrict__ bcv,
    float* __restrict__ Q)                    // [1280][1024] fp32
{
    __shared__ unsigned short As[2][64 * PADK];
    __shared__ unsigned short Bs[2][64 * PADK];

    const int tid = threadIdx.x;
    const int row0 = blockIdx.y << 6;   // 20 tiles
    const int col0 = blockIdx.x << 6;   // 16 tiles
    const int w = tid >> 6, lane = tid & 63;
    const int l16 = lane & 15, kq = lane >> 4;
    const int sr = tid >> 2, sk8 = (tid & 3) << 3;   // staging: row, k-offset

    const unsigned short* Arow = xbf + (size_t)(row0 + sr) * 512 + sk8;
    const unsigned short* Brow = WcT + (size_t)(col0 + sr) * 512 + sk8;

    bf16x8 areg, breg;
    auto loadg = [&](int kb) {
        areg = *reinterpret_cast<const bf16x8*>(Arow + kb);
        breg = *reinterpret_cast<const bf16x8*>(Brow + kb);
    };
    auto stage = [&](int buf) {
        *reinterpret_cast<bf16x8*>(&As[buf][sr * PADK + sk8]) = areg;
        *reinterpret_cast<bf16x8*>(&Bs[buf][sr * PADK + sk8]) = breg;
    };

    f32x4 acc[4] = {};
    loadg(0);
    stage(0);
    __syncthreads();
    int buf = 0;
    for (int kt = 0; kt < 16; ++kt) {
        if (kt < 15) loadg((kt + 1) << 5);
        bf16x8 a = *reinterpret_cast<const bf16x8*>(&As[buf][(w * 16 + l16) * PADK + kq * 8]);
        #pragma unroll
        for (int nf = 0; nf < 4; ++nf) {
            bf16x8 b = *reinterpret_cast<const bf16x8*>(&Bs[buf][(nf * 16 + l16) * PADK + kq * 8]);
            acc[nf] = __builtin_amdgcn_mfma_f32_16x16x32_bf16(a, b, acc[nf], 0, 0, 0);
        }
        if (kt < 15) stage(buf ^ 1);
        __syncthreads();
        buf ^= 1;
    }

    const int cr0 = row0 + w * 16 + kq * 4;
    const bool doBias = (row0 >= 1024);
    #pragma unroll
    for (int nf = 0; nf < 4; ++nf) {
        const int c = col0 + nf * 16 + l16;
        const float bv = doBias ? bcv[c] : 0.0f;
        #pragma unroll
        for (int r = 0; r < 4; ++r)
            Q[(size_t)(cr0 + r) * 1024 + c] = acc[nf][r] + bv;
    }
}

// ---------------- D3: bcast (R13-proven) ----------------
// Grid 2048 = 128 bt-groups x 2 uh x 8 vt. Thread preloads ye[8]+yp[8] vf4,
// then 64 pure NT stores (8 bt x 8 u outer product).
__global__ __launch_bounds__(256) void bcast_add(
    const vf4* __restrict__ Q, vf4* __restrict__ out)
{
    const int bid = blockIdx.x;
    const int g   = bid >> 4;            // 0..127
    const int uh  = (bid >> 3) & 1;
    const int vt  = bid & 7;
    const int bt0 = g << 3;
    const int b   = bt0 >> 9;
    const int u8  = threadIdx.x >> 5;    // 0..7
    const int c4  = threadIdx.x & 31;
    const int vcol = vt * 32 + c4;

    vf4 ye[8], yp[8];
    #pragma unroll
    for (int i = 0; i < 8; ++i)
        ye[i] = Q[(size_t)(bt0 + i) * 256 + vcol];
    const int urow0 = 1024 + b * 128 + uh * 64 + u8 * 8;
    #pragma unroll
    for (int i = 0; i < 8; ++i)
        yp[i] = Q[(size_t)(urow0 + i) * 256 + vcol];

    #pragma unroll
    for (int bt = 0; bt < 8; ++bt) {
        vf4* o = out + ((size_t)(bt0 + bt) * 128 + uh * 64 + u8 * 8) * 256 + vcol;
        #pragma unroll
        for (int uu = 0; uu < 8; ++uu) {
            __builtin_nontemporal_store(ye[bt] + yp[uu], o + (size_t)uu * 256);
        }
    }
}

extern "C" void kernel_launch(void* const* d_in, const int* in_sizes, int n_in,
                              void* d_out, int out_size, void* d_ws, size_t ws_size,
                              hipStream_t stream)
{
    const float* pred = (const float*)d_in[0];  // [2,128,512]
    const float* enc  = (const float*)d_in[1];  // [2,512,512]
    const float* W0   = (const float*)d_in[2];  // [512,512]
    const float* b0   = (const float*)d_in[3];  // [512]
    const float* W1   = (const float*)d_in[4];  // [512,1024]
    const float* b1   = (const float*)d_in[5];  // [1024]
    float* out = (float*)d_out;                 // [2,512,128,1024] fp32

    char* base = (char*)d_ws;
    unsigned short* xbf = (unsigned short*)base;                 // 1.31 MB
    unsigned short* WcT = (unsigned short*)(base + (2 << 20));   // 1.05 MB
    float* bcv          = (float*)(base + (4 << 20));            // 4 KB
    float* Q            = (float*)(base + (8 << 20));            // 5.24 MB

    // D1: Wc-GEMM (128) + x-convert (320) + bcv (4) = 452 blocks
    prep<<<452, 256, 0, stream>>>(pred, enc, W0, b0, W1, b1, xbf, WcT, bcv);

    // D2: Q = xbf@WcT (+bcv on pred rows), 320 blocks
    gemm_y<<<dim3(16, 20), 256, 0, stream>>>(xbf, WcT, bcv, Q);

    // D3: out = ye + yp (536 MB NT write)
    bcast_add<<<2048, 256, 0, stream>>>((const vf4*)Q, (vf4*)out);
}

// Round 15
// 114.916 us; speedup vs baseline: 1.1163x; 1.1163x over previous
//
#include <hip/hip_runtime.h>

// out[b,t,u,v] = ye[b,t,v] + yp[b,u,v]
//   ye = enc@W0@W1 (no biases), yp = (pred@W0 + b0)@W1 + b1.
// R15 (= R13 champion + clean D2 staging):
//   D1 (288 blocks): [0,160) GEMM1: P[1280][512] bf16 = [enc;pred]@W0 (+b0 pred rows)
//                    [160,288) W1T bf16[1024][512] = transpose(W1) convert
//   D2 (320 blocks): Q[1280][1024] fp32 = P@W1T (+b1 pred rows).
//                    Double-buffered, bf16x8 staging both sides, no f2bf in loop.
//   D3 (2048 blocks): bcast register outer-product, pure NT-store stream (R13).

typedef float vf4 __attribute__((ext_vector_type(4)));
typedef short bf16x8 __attribute__((ext_vector_type(8)));
typedef float f32x4 __attribute__((ext_vector_type(4)));
typedef unsigned short us4 __attribute__((ext_vector_type(4)));

#define PADK 40   // LDS row stride in bf16 (80B)

__device__ __forceinline__ unsigned short f2bf(float f) {
    union { float f; unsigned u; } v; v.f = f;
    const unsigned r = v.u + 0x7FFFu + ((v.u >> 16) & 1u);   // RNE
    return (unsigned short)(r >> 16);
}

// ---------------- D1: GEMM1 (160 blocks) + W1 transpose-convert (128 blocks) ----------------
__global__ __launch_bounds__(256) void prep(
    const float* __restrict__ pred, const float* __restrict__ enc,
    const float* __restrict__ W0, const float* __restrict__ b0,
    const float* __restrict__ W1,
    unsigned short* __restrict__ P,      // [1280][512] bf16
    unsigned short* __restrict__ W1T)    // [1024][512] bf16 (n-major)
{
    __shared__ unsigned short As[64 * PADK];    // GEMM1: [row][k]
    __shared__ unsigned short Bst[64 * PADK];   // GEMM1: [n][k]
    __shared__ unsigned short Tr[64 * 68];      // transpose tile [n][k]

    const int bid = blockIdx.x;
    const int tid = threadIdx.x;

    if (bid < 160) {
        // ---- GEMM1: 64x64 tile of P = [enc;pred]@W0 (+b0 on pred rows) ----
        const int tn = bid & 7, tm = bid >> 3;
        const int row0 = tm << 6, col0 = tn << 6;
        const int w = tid >> 6, lane = tid & 63;
        const int l16 = lane & 15, kq = lane >> 4;

        float4 ar[2], br[2];
        auto loadA = [&](int kb) {
            #pragma unroll
            for (int i = 0; i < 2; ++i) {
                const int idx = tid + (i << 8);
                const int r = idx >> 3, k4 = (idx & 7) << 2;
                const float* Arow = (row0 < 1024)
                    ? enc + (size_t)(row0 + r) * 512
                    : pred + (size_t)(row0 - 1024 + r) * 512;
                ar[i] = *reinterpret_cast<const float4*>(Arow + kb + k4);
            }
        };
        auto loadB = [&](int kb) {
            #pragma unroll
            for (int i = 0; i < 2; ++i) {
                const int idx = tid + (i << 8);
                const int kk = idx >> 4, n4 = (idx & 15) << 2;
                br[i] = *reinterpret_cast<const float4*>(
                    W0 + (size_t)(kb + kk) * 512 + col0 + n4);
            }
        };
        auto stage = [&]() {
            #pragma unroll
            for (int i = 0; i < 2; ++i) {
                const int idx = tid + (i << 8);
                const int r = idx >> 3, k4 = (idx & 7) << 2;
                us4 p = { f2bf(ar[i].x), f2bf(ar[i].y), f2bf(ar[i].z), f2bf(ar[i].w) };
                *reinterpret_cast<us4*>(&As[r * PADK + k4]) = p;
                const int kk = idx >> 4, n4 = (idx & 15) << 2;
                Bst[(n4 + 0) * PADK + kk] = f2bf(br[i].x);
                Bst[(n4 + 1) * PADK + kk] = f2bf(br[i].y);
                Bst[(n4 + 2) * PADK + kk] = f2bf(br[i].z);
                Bst[(n4 + 3) * PADK + kk] = f2bf(br[i].w);
            }
        };

        f32x4 acc[4] = {};
        loadA(0); loadB(0);
        for (int kt = 0; kt < 16; ++kt) {
            __syncthreads();
            stage();
            __syncthreads();
            if (kt < 15) { loadA((kt + 1) << 5); loadB((kt + 1) << 5); }
            bf16x8 a = *reinterpret_cast<const bf16x8*>(&As[(w * 16 + l16) * PADK + kq * 8]);
            #pragma unroll
            for (int nf = 0; nf < 4; ++nf) {
                bf16x8 b = *reinterpret_cast<const bf16x8*>(&Bst[(nf * 16 + l16) * PADK + kq * 8]);
                acc[nf] = __builtin_amdgcn_mfma_f32_16x16x32_bf16(a, b, acc[nf], 0, 0, 0);
            }
        }
        const int cr0 = row0 + w * 16 + kq * 4;
        const bool doBias = (row0 >= 1024);
        #pragma unroll
        for (int nf = 0; nf < 4; ++nf) {
            const int c = col0 + nf * 16 + l16;
            const float bv = doBias ? b0[c] : 0.0f;
            #pragma unroll
            for (int r = 0; r < 4; ++r)
                P[(size_t)(cr0 + r) * 512 + c] = f2bf(acc[nf][r] + bv);
        }
    } else {
        // ---- W1T[n][k] = bf16(W1[k][n]), 128 blocks of 64x64 tiles ----
        const int t  = bid - 160;
        const int kt = t >> 4;           // 8 k-tiles
        const int nt = t & 15;           // 16 n-tiles
        const int k0 = kt << 6, n0 = nt << 6;

        // load 64x64 fp32 coalesced: thread r=tid>>2 (row k), c0=(tid&3)*16
        {
            const int r = tid >> 2, c0 = (tid & 3) << 4;
            const float* src = W1 + (size_t)(k0 + r) * 1024 + n0 + c0;
            #pragma unroll
            for (int j = 0; j < 4; ++j) {
                const float4 v = *reinterpret_cast<const float4*>(src + (j << 2));
                const int c = c0 + (j << 2);
                Tr[(c + 0) * 68 + r] = f2bf(v.x);
                Tr[(c + 1) * 68 + r] = f2bf(v.y);
                Tr[(c + 2) * 68 + r] = f2bf(v.z);
                Tr[(c + 3) * 68 + r] = f2bf(v.w);
            }
        }
        __syncthreads();
        // store coalesced: thread rr=tid>>2 (row n), k8=(tid&3)*16
        {
            const int rr = tid >> 2, k8 = (tid & 3) << 4;
            unsigned short* dst = W1T + (size_t)(n0 + rr) * 512 + k0 + k8;
            *reinterpret_cast<bf16x8*>(dst) =
                *reinterpret_cast<const bf16x8*>(&Tr[rr * 68 + k8]);
            *reinterpret_cast<bf16x8*>(dst + 8) =
                *reinterpret_cast<const bf16x8*>(&Tr[rr * 68 + k8 + 8]);
        }
    }
}

// ---------------- D2: Q = P @ W1T^T (+b1 on pred rows) ----------------
// Double-buffered; both sides staged with one bf16x8 load + one bf16x8 LDS
// store per thread per K-step (no conversion work in the loop).
__global__ __launch_bounds__(256) void gemm_y(
    const unsigned short* __restrict__ P,     // [1280][512]
    const unsigned short* __restrict__ W1T,   // [1024][512]
    const float* __restrict__ b1,
    float* __restrict__ Q)                    // [1280][1024] fp32
{
    __shared__ unsigned short As[2][64 * PADK];
    __shared__ unsigned short Bs[2][64 * PADK];

    const int tid = threadIdx.x;
    const int row0 = blockIdx.y << 6;   // 20 tiles
    const int col0 = blockIdx.x << 6;   // 16 tiles
    const int w = tid >> 6, lane = tid & 63;
    const int l16 = lane & 15, kq = lane >> 4;
    const int sr = tid >> 2, sk8 = (tid & 3) << 3;

    const unsigned short* Arow = P + (size_t)(row0 + sr) * 512 + sk8;
    const unsigned short* Brow = W1T + (size_t)(col0 + sr) * 512 + sk8;

    bf16x8 areg, breg;
    auto loadg = [&](int kb) {
        areg = *reinterpret_cast<const bf16x8*>(Arow + kb);
        breg = *reinterpret_cast<const bf16x8*>(Brow + kb);
    };
    auto stage = [&](int buf) {
        *reinterpret_cast<bf16x8*>(&As[buf][sr * PADK + sk8]) = areg;
        *reinterpret_cast<bf16x8*>(&Bs[buf][sr * PADK + sk8]) = breg;
    };

    f32x4 acc[4] = {};
    loadg(0);
    stage(0);
    __syncthreads();
    int buf = 0;
    for (int kt = 0; kt < 16; ++kt) {
        if (kt < 15) loadg((kt + 1) << 5);
        bf16x8 a = *reinterpret_cast<const bf16x8*>(&As[buf][(w * 16 + l16) * PADK + kq * 8]);
        #pragma unroll
        for (int nf = 0; nf < 4; ++nf) {
            bf16x8 b = *reinterpret_cast<const bf16x8*>(&Bs[buf][(nf * 16 + l16) * PADK + kq * 8]);
            acc[nf] = __builtin_amdgcn_mfma_f32_16x16x32_bf16(a, b, acc[nf], 0, 0, 0);
        }
        if (kt < 15) stage(buf ^ 1);
        __syncthreads();
        buf ^= 1;
    }

    const int cr0 = row0 + w * 16 + kq * 4;
    const bool doBias = (row0 >= 1024);
    #pragma unroll
    for (int nf = 0; nf < 4; ++nf) {
        const int c = col0 + nf * 16 + l16;
        const float bv = doBias ? b1[c] : 0.0f;
        #pragma unroll
        for (int r = 0; r < 4; ++r)
            Q[(size_t)(cr0 + r) * 1024 + c] = acc[nf][r] + bv;
    }
}

// ---------------- D3: bcast (R13-proven) ----------------
// Grid 2048 = 128 bt-groups x 2 uh x 8 vt. Thread preloads ye[8]+yp[8] vf4,
// then 64 pure NT stores (8 bt x 8 u outer product).
__global__ __launch_bounds__(256) void bcast_add(
    const vf4* __restrict__ Q, vf4* __restrict__ out)
{
    const int bid = blockIdx.x;
    const int g   = bid >> 4;            // 0..127
    const int uh  = (bid >> 3) & 1;
    const int vt  = bid & 7;
    const int bt0 = g << 3;
    const int b   = bt0 >> 9;
    const int u8  = threadIdx.x >> 5;    // 0..7
    const int c4  = threadIdx.x & 31;
    const int vcol = vt * 32 + c4;

    vf4 ye[8], yp[8];
    #pragma unroll
    for (int i = 0; i < 8; ++i)
        ye[i] = Q[(size_t)(bt0 + i) * 256 + vcol];
    const int urow0 = 1024 + b * 128 + uh * 64 + u8 * 8;
    #pragma unroll
    for (int i = 0; i < 8; ++i)
        yp[i] = Q[(size_t)(urow0 + i) * 256 + vcol];

    #pragma unroll
    for (int bt = 0; bt < 8; ++bt) {
        vf4* o = out + ((size_t)(bt0 + bt) * 128 + uh * 64 + u8 * 8) * 256 + vcol;
        #pragma unroll
        for (int uu = 0; uu < 8; ++uu) {
            __builtin_nontemporal_store(ye[bt] + yp[uu], o + (size_t)uu * 256);
        }
    }
}

extern "C" void kernel_launch(void* const* d_in, const int* in_sizes, int n_in,
                              void* d_out, int out_size, void* d_ws, size_t ws_size,
                              hipStream_t stream)
{
    const float* pred = (const float*)d_in[0];  // [2,128,512]
    const float* enc  = (const float*)d_in[1];  // [2,512,512]
    const float* W0   = (const float*)d_in[2];  // [512,512]
    const float* b0   = (const float*)d_in[3];  // [512]
    const float* W1   = (const float*)d_in[4];  // [512,1024]
    const float* b1   = (const float*)d_in[5];  // [1024]
    float* out = (float*)d_out;                 // [2,512,128,1024] fp32

    char* base = (char*)d_ws;
    unsigned short* P   = (unsigned short*)base;                 // 1.31 MB
    unsigned short* W1T = (unsigned short*)(base + (2 << 20));   // 1.05 MB
    float* Q            = (float*)(base + (4 << 20));            // 5.24 MB

    // D1: GEMM1 (160 blocks) + W1 transpose-convert (128 blocks)
    prep<<<288, 256, 0, stream>>>(pred, enc, W0, b0, W1, P, W1T);

    // D2: Q = P@W1T (+b1 on pred rows), 320 blocks
    gemm_y<<<dim3(16, 20), 256, 0, stream>>>(P, W1T, b1, Q);

    // D3: out = ye + yp (536 MB NT write)
    bcast_add<<<2048, 256, 0, stream>>>((const vf4*)Q, (vf4*)out);
}

// Round 16
// 112.438 us; speedup vs baseline: 1.1409x; 1.0220x over previous
//
#include <hip/hip_runtime.h>

// out[b,t,u,v] = ye[b,t,v] + yp[b,u,v]
//   ye = enc@W0@W1 (no biases), yp = (pred@W0 + b0)@W1 + b1.
// R16 (= R15 + split-K=2 on D2):
//   D1 (288 blocks): [0,160) GEMM1: P[1280][512] bf16 = [enc;pred]@W0 (+b0 pred rows)
//                    [160,288) W1T bf16[1024][512] = transpose(W1) convert
//   D2 (640 blocks): Q[z][1280][1024] fp32 partials = P@W1T over K-half z
//                    (+b1 on pred rows via z==0). 2.5 blocks/CU vs R15's 1.25.
//   D3 (2048 blocks): bcast sums Q0+Q1 in preload, pure NT-store stream.

typedef float vf4 __attribute__((ext_vector_type(4)));
typedef short bf16x8 __attribute__((ext_vector_type(8)));
typedef float f32x4 __attribute__((ext_vector_type(4)));
typedef unsigned short us4 __attribute__((ext_vector_type(4)));

#define PADK 40   // LDS row stride in bf16 (80B)

__device__ __forceinline__ unsigned short f2bf(float f) {
    union { float f; unsigned u; } v; v.f = f;
    const unsigned r = v.u + 0x7FFFu + ((v.u >> 16) & 1u);   // RNE
    return (unsigned short)(r >> 16);
}

// ---------------- D1: GEMM1 (160 blocks) + W1 transpose-convert (128 blocks) ----------------
__global__ __launch_bounds__(256) void prep(
    const float* __restrict__ pred, const float* __restrict__ enc,
    const float* __restrict__ W0, const float* __restrict__ b0,
    const float* __restrict__ W1,
    unsigned short* __restrict__ P,      // [1280][512] bf16
    unsigned short* __restrict__ W1T)    // [1024][512] bf16 (n-major)
{
    __shared__ unsigned short As[64 * PADK];    // GEMM1: [row][k]
    __shared__ unsigned short Bst[64 * PADK];   // GEMM1: [n][k]
    __shared__ unsigned short Tr[64 * 68];      // transpose tile [n][k]

    const int bid = blockIdx.x;
    const int tid = threadIdx.x;

    if (bid < 160) {
        // ---- GEMM1: 64x64 tile of P = [enc;pred]@W0 (+b0 on pred rows) ----
        const int tn = bid & 7, tm = bid >> 3;
        const int row0 = tm << 6, col0 = tn << 6;
        const int w = tid >> 6, lane = tid & 63;
        const int l16 = lane & 15, kq = lane >> 4;

        float4 ar[2], br[2];
        auto loadA = [&](int kb) {
            #pragma unroll
            for (int i = 0; i < 2; ++i) {
                const int idx = tid + (i << 8);
                const int r = idx >> 3, k4 = (idx & 7) << 2;
                const float* Arow = (row0 < 1024)
                    ? enc + (size_t)(row0 + r) * 512
                    : pred + (size_t)(row0 - 1024 + r) * 512;
                ar[i] = *reinterpret_cast<const float4*>(Arow + kb + k4);
            }
        };
        auto loadB = [&](int kb) {
            #pragma unroll
            for (int i = 0; i < 2; ++i) {
                const int idx = tid + (i << 8);
                const int kk = idx >> 4, n4 = (idx & 15) << 2;
                br[i] = *reinterpret_cast<const float4*>(
                    W0 + (size_t)(kb + kk) * 512 + col0 + n4);
            }
        };
        auto stage = [&]() {
            #pragma unroll
            for (int i = 0; i < 2; ++i) {
                const int idx = tid + (i << 8);
                const int r = idx >> 3, k4 = (idx & 7) << 2;
                us4 p = { f2bf(ar[i].x), f2bf(ar[i].y), f2bf(ar[i].z), f2bf(ar[i].w) };
                *reinterpret_cast<us4*>(&As[r * PADK + k4]) = p;
                const int kk = idx >> 4, n4 = (idx & 15) << 2;
                Bst[(n4 + 0) * PADK + kk] = f2bf(br[i].x);
                Bst[(n4 + 1) * PADK + kk] = f2bf(br[i].y);
                Bst[(n4 + 2) * PADK + kk] = f2bf(br[i].z);
                Bst[(n4 + 3) * PADK + kk] = f2bf(br[i].w);
            }
        };

        f32x4 acc[4] = {};
        loadA(0); loadB(0);
        for (int kt = 0; kt < 16; ++kt) {
            __syncthreads();
            stage();
            __syncthreads();
            if (kt < 15) { loadA((kt + 1) << 5); loadB((kt + 1) << 5); }
            bf16x8 a = *reinterpret_cast<const bf16x8*>(&As[(w * 16 + l16) * PADK + kq * 8]);
            #pragma unroll
            for (int nf = 0; nf < 4; ++nf) {
                bf16x8 b = *reinterpret_cast<const bf16x8*>(&Bst[(nf * 16 + l16) * PADK + kq * 8]);
                acc[nf] = __builtin_amdgcn_mfma_f32_16x16x32_bf16(a, b, acc[nf], 0, 0, 0);
            }
        }
        const int cr0 = row0 + w * 16 + kq * 4;
        const bool doBias = (row0 >= 1024);
        #pragma unroll
        for (int nf = 0; nf < 4; ++nf) {
            const int c = col0 + nf * 16 + l16;
            const float bv = doBias ? b0[c] : 0.0f;
            #pragma unroll
            for (int r = 0; r < 4; ++r)
                P[(size_t)(cr0 + r) * 512 + c] = f2bf(acc[nf][r] + bv);
        }
    } else {
        // ---- W1T[n][k] = bf16(W1[k][n]), 128 blocks of 64x64 tiles ----
        const int t  = bid - 160;
        const int kt = t >> 4;           // 8 k-tiles
        const int nt = t & 15;           // 16 n-tiles
        const int k0 = kt << 6, n0 = nt << 6;

        {
            const int r = tid >> 2, c0 = (tid & 3) << 4;
            const float* src = W1 + (size_t)(k0 + r) * 1024 + n0 + c0;
            #pragma unroll
            for (int j = 0; j < 4; ++j) {
                const float4 v = *reinterpret_cast<const float4*>(src + (j << 2));
                const int c = c0 + (j << 2);
                Tr[(c + 0) * 68 + r] = f2bf(v.x);
                Tr[(c + 1) * 68 + r] = f2bf(v.y);
                Tr[(c + 2) * 68 + r] = f2bf(v.z);
                Tr[(c + 3) * 68 + r] = f2bf(v.w);
            }
        }
        __syncthreads();
        {
            const int rr = tid >> 2, k8 = (tid & 3) << 4;
            unsigned short* dst = W1T + (size_t)(n0 + rr) * 512 + k0 + k8;
            *reinterpret_cast<bf16x8*>(dst) =
                *reinterpret_cast<const bf16x8*>(&Tr[rr * 68 + k8]);
            *reinterpret_cast<bf16x8*>(dst + 8) =
                *reinterpret_cast<const bf16x8*>(&Tr[rr * 68 + k8 + 8]);
        }
    }
}

// ---------------- D2: Q[z] = P @ W1T^T over K-half z (+b1 via z==0) ----------------
__global__ __launch_bounds__(256) void gemm_y(
    const unsigned short* __restrict__ P,     // [1280][512]
    const unsigned short* __restrict__ W1T,   // [1024][512]
    const float* __restrict__ b1,
    float* __restrict__ Qbase)                // 2 x [1280][1024] fp32
{
    __shared__ unsigned short As[2][64 * PADK];
    __shared__ unsigned short Bs[2][64 * PADK];

    const int tid = threadIdx.x;
    const int row0 = blockIdx.y << 6;   // 20 tiles
    const int col0 = blockIdx.x << 6;   // 16 tiles
    const int z    = blockIdx.z;        // K-half
    const int kbeg = z << 8;            // 0 or 256
    float* __restrict__ Q = Qbase + (size_t)z * 1280 * 1024;

    const int w = tid >> 6, lane = tid & 63;
    const int l16 = lane & 15, kq = lane >> 4;
    const int sr = tid >> 2, sk8 = (tid & 3) << 3;

    const unsigned short* Arow = P + (size_t)(row0 + sr) * 512 + kbeg + sk8;
    const unsigned short* Brow = W1T + (size_t)(col0 + sr) * 512 + kbeg + sk8;

    bf16x8 areg, breg;
    auto loadg = [&](int kb) {
        areg = *reinterpret_cast<const bf16x8*>(Arow + kb);
        breg = *reinterpret_cast<const bf16x8*>(Brow + kb);
    };
    auto stage = [&](int buf) {
        *reinterpret_cast<bf16x8*>(&As[buf][sr * PADK + sk8]) = areg;
        *reinterpret_cast<bf16x8*>(&Bs[buf][sr * PADK + sk8]) = breg;
    };

    f32x4 acc[4] = {};
    loadg(0);
    stage(0);
    __syncthreads();
    int buf = 0;
    for (int kt = 0; kt < 8; ++kt) {
        if (kt < 7) loadg((kt + 1) << 5);
        bf16x8 a = *reinterpret_cast<const bf16x8*>(&As[buf][(w * 16 + l16) * PADK + kq * 8]);
        #pragma unroll
        for (int nf = 0; nf < 4; ++nf) {
            bf16x8 b = *reinterpret_cast<const bf16x8*>(&Bs[buf][(nf * 16 + l16) * PADK + kq * 8]);
            acc[nf] = __builtin_amdgcn_mfma_f32_16x16x32_bf16(a, b, acc[nf], 0, 0, 0);
        }
        if (kt < 7) stage(buf ^ 1);
        __syncthreads();
        buf ^= 1;
    }

    const int cr0 = row0 + w * 16 + kq * 4;
    const bool doBias = (z == 0) && (row0 >= 1024);
    #pragma unroll
    for (int nf = 0; nf < 4; ++nf) {
        const int c = col0 + nf * 16 + l16;
        const float bv = doBias ? b1[c] : 0.0f;
        #pragma unroll
        for (int r = 0; r < 4; ++r)
            Q[(size_t)(cr0 + r) * 1024 + c] = acc[nf][r] + bv;
    }
}

// ---------------- D3: bcast (R13 structure, sums 2 partials in preload) ----------------
// Grid 2048 = 128 bt-groups x 2 uh x 8 vt. Thread preloads ye[8]+yp[8] vf4
// (each = Q0+Q1), then 64 pure NT stores (8 bt x 8 u outer product).
__global__ __launch_bounds__(256) void bcast_add(
    const vf4* __restrict__ Q, vf4* __restrict__ out)
{
    const int bid = blockIdx.x;
    const int g   = bid >> 4;            // 0..127
    const int uh  = (bid >> 3) & 1;
    const int vt  = bid & 7;
    const int bt0 = g << 3;
    const int b   = bt0 >> 9;
    const int u8  = threadIdx.x >> 5;    // 0..7
    const int c4  = threadIdx.x & 31;
    const int vcol = vt * 32 + c4;
    const size_t zs = (size_t)1280 * 256;   // partial stride in vf4

    vf4 ye[8], yp[8];
    #pragma unroll
    for (int i = 0; i < 8; ++i) {
        const size_t o = (size_t)(bt0 + i) * 256 + vcol;
        ye[i] = Q[o] + Q[o + zs];
    }
    const int urow0 = 1024 + b * 128 + uh * 64 + u8 * 8;
    #pragma unroll
    for (int i = 0; i < 8; ++i) {
        const size_t o = (size_t)(urow0 + i) * 256 + vcol;
        yp[i] = Q[o] + Q[o + zs];
    }

    #pragma unroll
    for (int bt = 0; bt < 8; ++bt) {
        vf4* o = out + ((size_t)(bt0 + bt) * 128 + uh * 64 + u8 * 8) * 256 + vcol;
        #pragma unroll
        for (int uu = 0; uu < 8; ++uu) {
            __builtin_nontemporal_store(ye[bt] + yp[uu], o + (size_t)uu * 256);
        }
    }
}

extern "C" void kernel_launch(void* const* d_in, const int* in_sizes, int n_in,
                              void* d_out, int out_size, void* d_ws, size_t ws_size,
                              hipStream_t stream)
{
    const float* pred = (const float*)d_in[0];  // [2,128,512]
    const float* enc  = (const float*)d_in[1];  // [2,512,512]
    const float* W0   = (const float*)d_in[2];  // [512,512]
    const float* b0   = (const float*)d_in[3];  // [512]
    const float* W1   = (const float*)d_in[4];  // [512,1024]
    const float* b1   = (const float*)d_in[5];  // [1024]
    float* out = (float*)d_out;                 // [2,512,128,1024] fp32

    char* base = (char*)d_ws;
    unsigned short* P   = (unsigned short*)base;                 // 1.31 MB
    unsigned short* W1T = (unsigned short*)(base + (2 << 20));   // 1.05 MB
    float* Q            = (float*)(base + (4 << 20));            // 2 x 5.24 MB

    // D1: GEMM1 (160 blocks) + W1 transpose-convert (128 blocks)
    prep<<<288, 256, 0, stream>>>(pred, enc, W0, b0, W1, P, W1T);

    // D2: Q partials = P@W1T (+b1 via z==0), 640 blocks (2.5/CU)
    gemm_y<<<dim3(16, 20, 2), 256, 0, stream>>>(P, W1T, b1, Q);

    // D3: out = ye + yp (536 MB NT write)
    bcast_add<<<2048, 256, 0, stream>>>((const vf4*)Q, (vf4*)out);
}

// Round 17
// 111.584 us; speedup vs baseline: 1.1496x; 1.0076x over previous
//
#include <hip/hip_runtime.h>

// out[b,t,u,v] = ye[b,t,v] + yp[b,u,v]
//   ye = enc@W0@W1 (no biases), yp = (pred@W0 + b0)@W1 + b1.
// R17 (= R16 + D1 GEMM tiles 64x64 -> 32x64 for occupancy):
//   D1 (448 blocks): [0,320) GEMM1: P[1280][512] bf16 = [enc;pred]@W0 (+b0 pred rows)
//                    (32x64 tiles: 40 row-tiles x 8 col-tiles, 1.75 blocks/CU)
//                    [320,448) W1T bf16[1024][512] = transpose(W1) convert
//   D2 (640 blocks): Q[z][1280][1024] fp32 partials = P@W1T over K-half z
//                    (+b1 on pred rows via z==0).
//   D3 (2048 blocks): bcast sums Q0+Q1 in preload, pure NT-store stream.

typedef float vf4 __attribute__((ext_vector_type(4)));
typedef short bf16x8 __attribute__((ext_vector_type(8)));
typedef float f32x4 __attribute__((ext_vector_type(4)));
typedef unsigned short us4 __attribute__((ext_vector_type(4)));

#define PADK 40   // LDS row stride in bf16 (80B)

__device__ __forceinline__ unsigned short f2bf(float f) {
    union { float f; unsigned u; } v; v.f = f;
    const unsigned r = v.u + 0x7FFFu + ((v.u >> 16) & 1u);   // RNE
    return (unsigned short)(r >> 16);
}

// ---------------- D1: GEMM1 (320 blocks, 32x64 tiles) + W1 transpose (128 blocks) ----------------
__global__ __launch_bounds__(256) void prep(
    const float* __restrict__ pred, const float* __restrict__ enc,
    const float* __restrict__ W0, const float* __restrict__ b0,
    const float* __restrict__ W1,
    unsigned short* __restrict__ P,      // [1280][512] bf16
    unsigned short* __restrict__ W1T)    // [1024][512] bf16 (n-major)
{
    __shared__ unsigned short As[32 * PADK];    // GEMM1: [row][k]
    __shared__ unsigned short Bst[64 * PADK];   // GEMM1: [n][k]
    __shared__ unsigned short Tr[64 * 68];      // transpose tile [n][k]

    const int bid = blockIdx.x;
    const int tid = threadIdx.x;

    if (bid < 320) {
        // ---- GEMM1: 32x64 tile of P = [enc;pred]@W0 (+b0 on pred rows) ----
        const int tn = bid & 7, tm = bid >> 3;      // 8 col-tiles, 40 row-tiles
        const int row0 = tm << 5, col0 = tn << 6;
        const int w = tid >> 6, lane = tid & 63;
        const int rh = w & 1;            // row half (16 rows)
        const int ch = w >> 1;           // col half (32 cols = 2 nf tiles)
        const int l16 = lane & 15, kq = lane >> 4;

        float4 ar; float4 br[2];
        auto loadA = [&](int kb) {
            const int r = tid >> 3, k4 = (tid & 7) << 2;    // 32 rows, 8 thr/row
            const float* Arow = (row0 < 1024)
                ? enc + (size_t)(row0 + r) * 512
                : pred + (size_t)(row0 - 1024 + r) * 512;
            ar = *reinterpret_cast<const float4*>(Arow + kb + k4);
        };
        auto loadB = [&](int kb) {
            #pragma unroll
            for (int i = 0; i < 2; ++i) {
                const int idx = tid + (i << 8);
                const int kk = idx >> 4, n4 = (idx & 15) << 2;
                br[i] = *reinterpret_cast<const float4*>(
                    W0 + (size_t)(kb + kk) * 512 + col0 + n4);
            }
        };
        auto stage = [&]() {
            {
                const int r = tid >> 3, k4 = (tid & 7) << 2;
                us4 p = { f2bf(ar.x), f2bf(ar.y), f2bf(ar.z), f2bf(ar.w) };
                *reinterpret_cast<us4*>(&As[r * PADK + k4]) = p;
            }
            #pragma unroll
            for (int i = 0; i < 2; ++i) {
                const int idx = tid + (i << 8);
                const int kk = idx >> 4, n4 = (idx & 15) << 2;
                Bst[(n4 + 0) * PADK + kk] = f2bf(br[i].x);
                Bst[(n4 + 1) * PADK + kk] = f2bf(br[i].y);
                Bst[(n4 + 2) * PADK + kk] = f2bf(br[i].z);
                Bst[(n4 + 3) * PADK + kk] = f2bf(br[i].w);
            }
        };

        f32x4 acc[2] = {};
        loadA(0); loadB(0);
        for (int kt = 0; kt < 16; ++kt) {
            __syncthreads();
            stage();
            __syncthreads();
            if (kt < 15) { loadA((kt + 1) << 5); loadB((kt + 1) << 5); }
            bf16x8 a = *reinterpret_cast<const bf16x8*>(&As[(rh * 16 + l16) * PADK + kq * 8]);
            #pragma unroll
            for (int nf = 0; nf < 2; ++nf) {
                bf16x8 b = *reinterpret_cast<const bf16x8*>(
                    &Bst[(ch * 32 + nf * 16 + l16) * PADK + kq * 8]);
                acc[nf] = __builtin_amdgcn_mfma_f32_16x16x32_bf16(a, b, acc[nf], 0, 0, 0);
            }
        }
        const int cr0 = row0 + rh * 16 + kq * 4;
        const bool doBias = (row0 >= 1024);
        #pragma unroll
        for (int nf = 0; nf < 2; ++nf) {
            const int c = col0 + ch * 32 + nf * 16 + l16;
            const float bv = doBias ? b0[c] : 0.0f;
            #pragma unroll
            for (int r = 0; r < 4; ++r)
                P[(size_t)(cr0 + r) * 512 + c] = f2bf(acc[nf][r] + bv);
        }
    } else {
        // ---- W1T[n][k] = bf16(W1[k][n]), 128 blocks of 64x64 tiles ----
        const int t  = bid - 320;
        const int kt = t >> 4;           // 8 k-tiles
        const int nt = t & 15;           // 16 n-tiles
        const int k0 = kt << 6, n0 = nt << 6;

        {
            const int r = tid >> 2, c0 = (tid & 3) << 4;
            const float* src = W1 + (size_t)(k0 + r) * 1024 + n0 + c0;
            #pragma unroll
            for (int j = 0; j < 4; ++j) {
                const float4 v = *reinterpret_cast<const float4*>(src + (j << 2));
                const int c = c0 + (j << 2);
                Tr[(c + 0) * 68 + r] = f2bf(v.x);
                Tr[(c + 1) * 68 + r] = f2bf(v.y);
                Tr[(c + 2) * 68 + r] = f2bf(v.z);
                Tr[(c + 3) * 68 + r] = f2bf(v.w);
            }
        }
        __syncthreads();
        {
            const int rr = tid >> 2, k8 = (tid & 3) << 4;
            unsigned short* dst = W1T + (size_t)(n0 + rr) * 512 + k0 + k8;
            *reinterpret_cast<bf16x8*>(dst) =
                *reinterpret_cast<const bf16x8*>(&Tr[rr * 68 + k8]);
            *reinterpret_cast<bf16x8*>(dst + 8) =
                *reinterpret_cast<const bf16x8*>(&Tr[rr * 68 + k8 + 8]);
        }
    }
}

// ---------------- D2: Q[z] = P @ W1T^T over K-half z (+b1 via z==0) ----------------
__global__ __launch_bounds__(256) void gemm_y(
    const unsigned short* __restrict__ P,     // [1280][512]
    const unsigned short* __restrict__ W1T,   // [1024][512]
    const float* __restrict__ b1,
    float* __restrict__ Qbase)                // 2 x [1280][1024] fp32
{
    __shared__ unsigned short As[2][64 * PADK];
    __shared__ unsigned short Bs[2][64 * PADK];

    const int tid = threadIdx.x;
    const int row0 = blockIdx.y << 6;   // 20 tiles
    const int col0 = blockIdx.x << 6;   // 16 tiles
    const int z    = blockIdx.z;        // K-half
    const int kbeg = z << 8;            // 0 or 256
    float* __restrict__ Q = Qbase + (size_t)z * 1280 * 1024;

    const int w = tid >> 6, lane = tid & 63;
    const int l16 = lane & 15, kq = lane >> 4;
    const int sr = tid >> 2, sk8 = (tid & 3) << 3;

    const unsigned short* Arow = P + (size_t)(row0 + sr) * 512 + kbeg + sk8;
    const unsigned short* Brow = W1T + (size_t)(col0 + sr) * 512 + kbeg + sk8;

    bf16x8 areg, breg;
    auto loadg = [&](int kb) {
        areg = *reinterpret_cast<const bf16x8*>(Arow + kb);
        breg = *reinterpret_cast<const bf16x8*>(Brow + kb);
    };
    auto stage = [&](int buf) {
        *reinterpret_cast<bf16x8*>(&As[buf][sr * PADK + sk8]) = areg;
        *reinterpret_cast<bf16x8*>(&Bs[buf][sr * PADK + sk8]) = breg;
    };

    f32x4 acc[4] = {};
    loadg(0);
    stage(0);
    __syncthreads();
    int buf = 0;
    for (int kt = 0; kt < 8; ++kt) {
        if (kt < 7) loadg((kt + 1) << 5);
        bf16x8 a = *reinterpret_cast<const bf16x8*>(&As[buf][(w * 16 + l16) * PADK + kq * 8]);
        #pragma unroll
        for (int nf = 0; nf < 4; ++nf) {
            bf16x8 b = *reinterpret_cast<const bf16x8*>(&Bs[buf][(nf * 16 + l16) * PADK + kq * 8]);
            acc[nf] = __builtin_amdgcn_mfma_f32_16x16x32_bf16(a, b, acc[nf], 0, 0, 0);
        }
        if (kt < 7) stage(buf ^ 1);
        __syncthreads();
        buf ^= 1;
    }

    const int cr0 = row0 + w * 16 + kq * 4;
    const bool doBias = (z == 0) && (row0 >= 1024);
    #pragma unroll
    for (int nf = 0; nf < 4; ++nf) {
        const int c = col0 + nf * 16 + l16;
        const float bv = doBias ? b1[c] : 0.0f;
        #pragma unroll
        for (int r = 0; r < 4; ++r)
            Q[(size_t)(cr0 + r) * 1024 + c] = acc[nf][r] + bv;
    }
}

// ---------------- D3: bcast (R13 structure, sums 2 partials in preload) ----------------
__global__ __launch_bounds__(256) void bcast_add(
    const vf4* __restrict__ Q, vf4* __restrict__ out)
{
    const int bid = blockIdx.x;
    const int g   = bid >> 4;            // 0..127
    const int uh  = (bid >> 3) & 1;
    const int vt  = bid & 7;
    const int bt0 = g << 3;
    const int b   = bt0 >> 9;
    const int u8  = threadIdx.x >> 5;    // 0..7
    const int c4  = threadIdx.x & 31;
    const int vcol = vt * 32 + c4;
    const size_t zs = (size_t)1280 * 256;   // partial stride in vf4

    vf4 ye[8], yp[8];
    #pragma unroll
    for (int i = 0; i < 8; ++i) {
        const size_t o = (size_t)(bt0 + i) * 256 + vcol;
        ye[i] = Q[o] + Q[o + zs];
    }
    const int urow0 = 1024 + b * 128 + uh * 64 + u8 * 8;
    #pragma unroll
    for (int i = 0; i < 8; ++i) {
        const size_t o = (size_t)(urow0 + i) * 256 + vcol;
        yp[i] = Q[o] + Q[o + zs];
    }

    #pragma unroll
    for (int bt = 0; bt < 8; ++bt) {
        vf4* o = out + ((size_t)(bt0 + bt) * 128 + uh * 64 + u8 * 8) * 256 + vcol;
        #pragma unroll
        for (int uu = 0; uu < 8; ++uu) {
            __builtin_nontemporal_store(ye[bt] + yp[uu], o + (size_t)uu * 256);
        }
    }
}

extern "C" void kernel_launch(void* const* d_in, const int* in_sizes, int n_in,
                              void* d_out, int out_size, void* d_ws, size_t ws_size,
                              hipStream_t stream)
{
    const float* pred = (const float*)d_in[0];  // [2,128,512]
    const float* enc  = (const float*)d_in[1];  // [2,512,512]
    const float* W0   = (const float*)d_in[2];  // [512,512]
    const float* b0   = (const float*)d_in[3];  // [512]
    const float* W1   = (const float*)d_in[4];  // [512,1024]
    const float* b1   = (const float*)d_in[5];  // [1024]
    float* out = (float*)d_out;                 // [2,512,128,1024] fp32

    char* base = (char*)d_ws;
    unsigned short* P   = (unsigned short*)base;                 // 1.31 MB
    unsigned short* W1T = (unsigned short*)(base + (2 << 20));   // 1.05 MB
    float* Q            = (float*)(base + (4 << 20));            // 2 x 5.24 MB

    // D1: GEMM1 (320 blocks, 32x64 tiles) + W1 transpose-convert (128 blocks)
    prep<<<448, 256, 0, stream>>>(pred, enc, W0, b0, W1, P, W1T);

    // D2: Q partials = P@W1T (+b1 via z==0), 640 blocks (2.5/CU)
    gemm_y<<<dim3(16, 20, 2), 256, 0, stream>>>(P, W1T, b1, Q);

    // D3: out = ye + yp (536 MB NT write)
    bcast_add<<<2048, 256, 0, stream>>>((const vf4*)Q, (vf4*)out);
}